// Round 4
// baseline (345.660 us; speedup 1.0000x reference)
//
#include <hip/hip_runtime.h>

#define TOK 65536
#define DM 256
#define DF 1024
#define NB 4

typedef unsigned short ushort_t;
typedef unsigned int uint32;

typedef __attribute__((ext_vector_type(8))) short bf16x8;
typedef __attribute__((ext_vector_type(4))) float f32x4;
typedef __attribute__((ext_vector_type(4))) uint32 u32x4;

__device__ inline ushort_t f2bf(float f) {
  union { float f; unsigned int u; } v; v.f = f;
  unsigned int u = v.u;
  unsigned int r = (u + 0x7FFFu + ((u >> 16) & 1u)) >> 16;
  return (ushort_t)r;
}
__device__ inline float bf2f(ushort_t u) {
  union { unsigned int u; float f; } v; v.u = ((uint32)u) << 16; return v.f;
}
__device__ inline uint32 pack2(float a, float b) {
  return (uint32)f2bf(a) | ((uint32)f2bf(b) << 16);
}

// async global->LDS DMA, 16 B/lane: LDS dest = wave-uniform base + lane*16.
__device__ __forceinline__ void dma16(const ushort_t* g, ushort_t* lds) {
  __builtin_amdgcn_global_load_lds(
      (const __attribute__((address_space(1))) unsigned int*)(const void*)g,
      (__attribute__((address_space(3))) unsigned int*)(void*)lds,
      16, 0, 0);
}

// ---------------- kernel 0: convert w1/w2 fp32 -> bf16 + zero counts --------
__global__ __launch_bounds__(256) void prep_weights_kernel(
    const float* __restrict__ w1, const float* __restrict__ w2,
    ushort_t* __restrict__ w1b, ushort_t* __restrict__ w2b,
    int* __restrict__ counts)
{
  if (blockIdx.x == 0 && blockIdx.y == 0 && threadIdx.x < NB)
    counts[threadIdx.x] = 0;
  const int idx = blockIdx.x * 256 + threadIdx.x;
  const float* src = blockIdx.y ? w2 : w1;
  ushort_t* dst = blockIdx.y ? w2b : w1b;
  f32x4 v = *(const f32x4*)(src + (size_t)idx * 4);
  uint2 p;
  p.x = pack2(v.x, v.y);
  p.y = pack2(v.z, v.w);
  *(uint2*)(dst + (size_t)idx * 4) = p;
}

// ---------------- kernel 1: route tokens to per-branch lists + zero-fill ----
__global__ __launch_bounds__(256) void route_kernel(
    const int* __restrict__ b_seq, int* __restrict__ counts,
    ushort_t* __restrict__ lists, u32x4* __restrict__ out16)
{
  __shared__ int s_lpos[NB];
  __shared__ int s_lbase[NB];
  __shared__ int s_b[256];
  const int tid = threadIdx.x;
  const int base = blockIdx.x * 256;
  const int token = base + tid;
  if (tid < NB) s_lpos[tid] = 0;
  __syncthreads();
  const int b = b_seq[token];
  s_b[tid] = b;
  int my = 0;
  if (b > 0) my = atomicAdd(&s_lpos[b - 1], 1);
  __syncthreads();
  if (tid < NB) s_lbase[tid] = atomicAdd(&counts[tid], s_lpos[tid]);
  __syncthreads();
  if (b > 0) lists[(b - 1) * TOK + s_lbase[b - 1] + my] = (ushort_t)token;
  // zero-fill rows with b==0, 16 B per store (64 u32x4 per row of 256 f32)
  const u32x4 z = (u32x4){0u, 0u, 0u, 0u};
  #pragma unroll 4
  for (int it = 0; it < 64; ++it) {
    int flat = it * 256 + tid;
    int tl = flat >> 6;          // wave-uniform row
    int j = flat & 63;
    if (s_b[tl] == 0) out16[(size_t)(base + tl) * 64 + j] = z;
  }
}

// ---------------- kernel 2: wave-specialized FFN + LN ----------------------
// Round-3 lesson: LDS pipe is the bottleneck (136 b128-reads/chunk ~ 2.2k cyc
// vs 154 MFMA cyc/SIMD; occupancy 2x gave only 6%). Fix: producer/consumer
// wave specialization. Block = 8 waves (512 thr), M=64 tokens, 32 chunks F=32.
//   waves 0-3 (G1): GEMM1 only. xfrag[2][8]=64 VGPR, NO yacc.
//     wave (fi=wv&1, th=wv>>1): H[32 tok x 16 f], 8 B-reads -> 16 MFMA
//     (mi2 reuse => W1 read 2x/block, was 4x).
//   waves 4-7 (G2): GEMM2 only. yacc[2][8]=64 AGPR, NO xfrag.
//     wave (dh=wv&1, th): Y[32 tok x 128 d], 8 B-reads -> 16 MFMA (W2 2x).
// Disjoint if/else (scalar branch via readfirstlane) keeps the two 64-reg
// states from ever being co-live => ~110 unified/branch <= 128 cap => still
// 2 blocks/CU, 16 waves/CU. Software pipeline: G1 computes chunk i while G2
// consumes chunk i-1 (sH double-buffered) => ONE barrier/iteration (was 2).
// LDS reads/chunk: 72 b128 (was 136). Barrier counts match on both paths:
// B0,B1,B2 + 33 loop + E1,E2.
__global__ __launch_bounds__(512, 4) void ffn_kernel(
    const float* __restrict__ x,
    const ushort_t* __restrict__ w1b_all, const float* __restrict__ b1,
    const ushort_t* __restrict__ w2b_all, const float* __restrict__ b2,
    const float* __restrict__ gamma, const float* __restrict__ beta,
    const int* __restrict__ counts, const ushort_t* __restrict__ lists,
    float* __restrict__ out)
{
  const int id = blockIdx.x;
  const int slot = id & 7;            // XCD affinity: branch n -> XCDs {2n,2n+1}
  const int n = slot >> 1;
  const int tile = ((id >> 3) << 1) + (slot & 1);
  const int cnt = counts[n];
  const int tile0 = tile * 64;
  if (tile0 >= cnt) return;           // block-uniform exit (before any barrier)
  const int mvalid = min(64, cnt - tile0);

  __shared__ __align__(16) ushort_t sW1[2][8192];   // 2 x 16KB (32f x 256k)
  __shared__ __align__(16) ushort_t sW2[2][8192];   // 2 x 16KB (256d x 32f)
  __shared__ __align__(16) ushort_t sH[2][64][40];  // H double-buffer
  __shared__ ushort_t sB1[DF];        // b1 as bf16 (exact for b1==0)
  __shared__ int s_idx[64];
  __shared__ float s_ps[2][64];
  __shared__ float s_pq[2][64];
  __shared__ float s_mu[64];
  __shared__ float s_rs[64];
  // total 79,616 B -> 2 blocks/CU

  ushort_t (*sX)[256] = (ushort_t (*)[256])&sW1[0][0];  // prologue alias 32KB

  const int tid  = threadIdx.x;
  const int wv   = tid >> 6;          // 0..7
  const int lane = tid & 63;
  const int q    = lane >> 4;
  const int lc   = lane & 15;
  const int wvu  = __builtin_amdgcn_readfirstlane(wv);  // force scalar branch

  const ushort_t* w1b = w1b_all + (size_t)n * DF * DM;
  const ushort_t* w2b = w2b_all + (size_t)n * DM * DF;

  if (tid < 64) {
    int i = tile0 + tid;
    s_idx[tid] = (int)lists[n * TOK + (i < cnt ? i : tile0)];
  }
  if (tid < 256) {
    f32x4 v = *(const f32x4*)(b1 + n * DF + tid * 4);
    uint2 p;
    p.x = pack2(v.x, v.y);
    p.y = pack2(v.z, v.w);
    *(uint2*)(sB1 + tid * 4) = p;
  }
  __syncthreads();                    // B0: s_idx ready

  // ---- stage X tile 64x256 fp32 -> bf16 into sX, 16B-granule XOR swizzle
  #pragma unroll
  for (int it = 0; it < 4; ++it) {
    int flat = it * 512 + tid;
    int r = flat >> 5;                 // 0..63
    int c8 = flat & 31;                // 16B granule (8 bf16)
    const float* xp = x + (size_t)s_idx[r] * DM + c8 * 8;
    f32x4 a = *(const f32x4*)xp;
    f32x4 c = *(const f32x4*)(xp + 4);
    u32x4 p;
    p.x = pack2(a.x, a.y); p.y = pack2(a.z, a.w);
    p.z = pack2(c.x, c.y); p.w = pack2(c.z, c.w);
    *(u32x4*)(&sX[r][(c8 ^ (r & 31)) * 8]) = p;
  }
  __syncthreads();                    // B1: sX ready

  bf16x8 xfrag[2][8];
  if (wvu < 4) {
    const int th = wv >> 1;
    #pragma unroll
    for (int mi2 = 0; mi2 < 2; ++mi2)
      #pragma unroll
      for (int ks = 0; ks < 8; ++ks) {
        int row = th * 32 + mi2 * 16 + lc;
        int g = (ks * 4 + q) ^ (row & 31);
        xfrag[mi2][ks] = *(const bf16x8*)(&sX[row][g * 8]);
      }
  }
  __syncthreads();                    // B2: sX dead, W1 bufs free

  if (wvu < 4) {
    // =================== producer: GEMM1 (waves 0-3) =======================
    const int fi = wv & 1;
    const int th = wv >> 1;
    auto issue_w1 = [&](int fc1) {
      ushort_t* dst = sW1[fc1 & 1];
      const ushort_t* g1 = w1b + (size_t)(fc1 * 32) * DM;
      #pragma unroll
      for (int j = 0; j < 4; ++j) {
        int i = (wv & 3) * 4 + j;       // 16 x 1KB segs over 4 waves
        int s = i * 64 + lane;
        int r1 = s >> 5, cp1 = s & 31;  // r1 in 0..31
        dma16(g1 + (size_t)r1 * DM + (size_t)(cp1 ^ r1) * 8, dst + i * 512);
      }
    };
    issue_w1(0);
    const int r = fi * 16 + lc;         // W1 local row (0..31)
    #pragma unroll 1
    for (int i = 0; i <= 32; ++i) {
      __builtin_amdgcn_sched_barrier(0);
      __builtin_amdgcn_s_waitcnt(0x0070);   // vmcnt(0) lgkmcnt(0)
      __builtin_amdgcn_s_barrier();
      __builtin_amdgcn_sched_barrier(0);
      if (i < 31) issue_w1(i + 1);
      if (i < 32) {
        const ushort_t* w1row = sW1[i & 1] + r * 256;
        const float b1v = bf2f(sB1[i * 32 + fi * 16 + lc]);
        f32x4 h0 = (f32x4){0.f, 0.f, 0.f, 0.f};
        f32x4 h1 = (f32x4){0.f, 0.f, 0.f, 0.f};
        __builtin_amdgcn_s_setprio(1);
        #pragma unroll
        for (int ks = 0; ks < 8; ++ks) {
          int cp = (ks * 4 + q) ^ r;
          bf16x8 bf = *(const bf16x8*)(w1row + cp * 8);
          h0 = __builtin_amdgcn_mfma_f32_16x16x32_bf16(xfrag[0][ks], bf, h0, 0, 0, 0);
          h1 = __builtin_amdgcn_mfma_f32_16x16x32_bf16(xfrag[1][ks], bf, h1, 0, 0, 0);
        }
        __builtin_amdgcn_s_setprio(0);
        #pragma unroll
        for (int r4 = 0; r4 < 4; ++r4) {
          float v0 = h0[r4] + b1v;
          v0 = (v0 > 0.f) ? v0 : (__expf(v0) - 1.f);
          sH[i & 1][th * 32 + q * 4 + r4][fi * 16 + lc] = f2bf(v0);
          float v1 = h1[r4] + b1v;
          v1 = (v1 > 0.f) ? v1 : (__expf(v1) - 1.f);
          sH[i & 1][th * 32 + 16 + q * 4 + r4][fi * 16 + lc] = f2bf(v1);
        }
      }
    }
    // epilogue participation: barrier count must match consumer (E1, E2)
    __syncthreads();
    __syncthreads();
  } else {
    // =================== consumer: GEMM2 (waves 4-7) =======================
    const int dh = wv & 1;
    const int th = (wv >> 1) & 1;
    auto issue_w2 = [&](int fc2) {
      ushort_t* dst = sW2[fc2 & 1];
      const ushort_t* g2 = w2b + fc2 * 32;
      const int g = wv - 4;             // 0..3
      #pragma unroll
      for (int j = 0; j < 4; ++j) {
        int i = g * 4 + j;              // 16 x 1KB segs over 4 waves
        int s = i * 64 + lane;
        int d2 = s >> 2, cp2 = s & 3;
        int cps = cp2 ^ (d2 & 3) ^ ((d2 >> 2) & 3);
        dma16(g2 + (size_t)d2 * DF + (size_t)cps * 8, dst + i * 512);
      }
    };
    f32x4 yacc[2][8];                   // [mi2][di]: 32 tok x 128 d (64 AGPR)
    #pragma unroll
    for (int mi2 = 0; mi2 < 2; ++mi2)
      #pragma unroll
      for (int di = 0; di < 8; ++di)
        yacc[mi2][di] = (f32x4){0.f, 0.f, 0.f, 0.f};
    const int cpw = (q ^ (lc & 3) ^ ((lc >> 2) & 3)) * 8;
    #pragma unroll 1
    for (int i = 0; i <= 32; ++i) {
      __builtin_amdgcn_sched_barrier(0);
      __builtin_amdgcn_s_waitcnt(0x0070);   // vmcnt(0) lgkmcnt(0)
      __builtin_amdgcn_s_barrier();
      __builtin_amdgcn_sched_barrier(0);
      if (i < 32) issue_w2(i);
      if (i >= 1) {
        const int rb = (i - 1) & 1;
        bf16x8 af[2];
        #pragma unroll
        for (int mi2 = 0; mi2 < 2; ++mi2)
          af[mi2] = *(const bf16x8*)(&sH[rb][th * 32 + mi2 * 16 + lc][q * 8]);
        const ushort_t* w2base = &sW2[rb][0] + (size_t)(dh * 128 + lc) * 32 + cpw;
        __builtin_amdgcn_s_setprio(1);
        #pragma unroll
        for (int di = 0; di < 8; ++di) {
          bf16x8 bf = *(const bf16x8*)(w2base + di * 512);
          yacc[0][di] = __builtin_amdgcn_mfma_f32_16x16x32_bf16(af[0], bf, yacc[0][di], 0, 0, 0);
          yacc[1][di] = __builtin_amdgcn_mfma_f32_16x16x32_bf16(af[1], bf, yacc[1][di], 0, 0, 0);
        }
        __builtin_amdgcn_s_setprio(0);
      }
    }

    // ============== epilogue: +b2, LN stats, gamma/beta, store =============
    float b2v[8], gv[8], bv[8];
    #pragma unroll
    for (int di = 0; di < 8; ++di) {
      int dcol = n * DM + dh * 128 + di * 16 + lc;
      b2v[di] = b2[dcol];
      gv[di]  = gamma[dcol];
      bv[di]  = beta[dcol];
    }
    #pragma unroll
    for (int mi2 = 0; mi2 < 2; ++mi2)
      #pragma unroll
      for (int di = 0; di < 8; ++di)
        #pragma unroll
        for (int r4 = 0; r4 < 4; ++r4)
          yacc[mi2][di][r4] += b2v[di];

    #pragma unroll
    for (int mi2 = 0; mi2 < 2; ++mi2) {
      #pragma unroll
      for (int r4 = 0; r4 < 4; ++r4) {
        float s = 0.f, sq = 0.f;
        #pragma unroll
        for (int di = 0; di < 8; ++di) {
          float v = yacc[mi2][di][r4];
          s += v; sq += v * v;
        }
        #pragma unroll
        for (int off = 1; off < 16; off <<= 1) {
          s  += __shfl_xor(s, off, 64);
          sq += __shfl_xor(sq, off, 64);
        }
        if (lc == 0) {
          int tok = th * 32 + mi2 * 16 + q * 4 + r4;
          s_ps[dh][tok] = s;
          s_pq[dh][tok] = sq;
        }
      }
    }
    __syncthreads();                    // E1
    if (wv == 4) {                      // one G2 wave combines (lane 0..63)
      float s  = s_ps[0][lane] + s_ps[1][lane];
      float sq = s_pq[0][lane] + s_pq[1][lane];
      float mu = s * (1.f / 256.f);
      float var = fmaxf(sq * (1.f / 256.f) - mu * mu, 0.f);
      s_mu[lane] = mu;
      s_rs[lane] = rsqrtf(var + 1e-12f);
    }
    __syncthreads();                    // E2

    #pragma unroll
    for (int mi2 = 0; mi2 < 2; ++mi2) {
      #pragma unroll
      for (int r4 = 0; r4 < 4; ++r4) {
        int tok = th * 32 + mi2 * 16 + q * 4 + r4;
        if (tok < mvalid) {
          float mu = s_mu[tok], rs = s_rs[tok];
          size_t rowbase = (size_t)s_idx[tok] * DM + dh * 128;
          #pragma unroll
          for (int di = 0; di < 8; ++di) {
            float v = (yacc[mi2][di][r4] - mu) * rs * gv[di] + bv[di];
            out[rowbase + di * 16 + lc] = v;
          }
        }
      }
    }
  }
}

extern "C" void kernel_launch(void* const* d_in, const int* in_sizes, int n_in,
                              void* d_out, int out_size, void* d_ws, size_t ws_size,
                              hipStream_t stream) {
  const float* x     = (const float*)d_in[0];
  const int*   b_seq = (const int*)d_in[1];
  const float* w1    = (const float*)d_in[2];
  const float* b1    = (const float*)d_in[3];
  const float* w2    = (const float*)d_in[4];
  const float* b2    = (const float*)d_in[5];
  const float* gamma = (const float*)d_in[6];
  const float* beta  = (const float*)d_in[7];
  float* out = (float*)d_out;

  int* counts = (int*)d_ws;
  ushort_t* lists = (ushort_t*)((char*)d_ws + 256);                 // 512 KB
  ushort_t* w1b = (ushort_t*)((char*)d_ws + 256 + 512 * 1024);      // 2 MB
  ushort_t* w2b = w1b + (size_t)NB * DF * DM;                       // 2 MB

  hipLaunchKernelGGL(prep_weights_kernel, dim3(1024, 2), dim3(256), 0, stream,
                     w1, w2, w1b, w2b, counts);
  hipLaunchKernelGGL(route_kernel, dim3(TOK / 256), dim3(256), 0, stream,
                     b_seq, counts, lists, (u32x4*)d_out);
  // 1024 tiles/branch capacity: covers any branch imbalance up to 65536
  hipLaunchKernelGGL(ffn_kernel, dim3(4096), dim3(512), 0, stream,
                     x, w1b, b1, w2b, b2, gamma, beta, counts, lists, out);
}

// Round 5
// 225.789 us; speedup vs baseline: 1.5309x; 1.5309x over previous
//
#include <hip/hip_runtime.h>

#define TOK 65536
#define DM 256
#define DF 1024
#define NB 4

typedef unsigned short ushort_t;
typedef unsigned int uint32;

typedef __attribute__((ext_vector_type(8))) short bf16x8;
typedef __attribute__((ext_vector_type(4))) float f32x4;
typedef __attribute__((ext_vector_type(4))) uint32 u32x4;

__device__ inline ushort_t f2bf(float f) {
  union { float f; unsigned int u; } v; v.f = f;
  unsigned int u = v.u;
  unsigned int r = (u + 0x7FFFu + ((u >> 16) & 1u)) >> 16;
  return (ushort_t)r;
}
__device__ inline float bf2f(ushort_t u) {
  union { unsigned int u; float f; } v; v.u = ((uint32)u) << 16; return v.f;
}
__device__ inline uint32 pack2(float a, float b) {
  return (uint32)f2bf(a) | ((uint32)f2bf(b) << 16);
}

// async global->LDS DMA, 16 B/lane: LDS dest = wave-uniform base + lane*16.
__device__ __forceinline__ void dma16(const ushort_t* g, ushort_t* lds) {
  __builtin_amdgcn_global_load_lds(
      (const __attribute__((address_space(1))) unsigned int*)(const void*)g,
      (__attribute__((address_space(3))) unsigned int*)(void*)lds,
      16, 0, 0);
}

// ------- kernel 0: merged weight-convert + token-route (+ zero-fill) -------
// blocks [0,256): route 256 tokens each (counts pre-zeroed by hipMemsetAsync)
// blocks [256,2304): w1/w2 fp32 -> bf16 conversion
__global__ __launch_bounds__(256) void prep_route_kernel(
    const float* __restrict__ w1, const float* __restrict__ w2,
    ushort_t* __restrict__ w1b, ushort_t* __restrict__ w2b,
    const int* __restrict__ b_seq, int* __restrict__ counts,
    ushort_t* __restrict__ lists, u32x4* __restrict__ out16)
{
  const int bx = blockIdx.x;
  const int tid = threadIdx.x;
  if (bx >= 256) {
    // ---- weight conversion branch (no barriers on this path)
    const int pb = bx - 256;             // 0..2047
    const int idx = (pb & 1023) * 256 + tid;
    const float* src = (pb >> 10) ? w2 : w1;
    ushort_t* dst = (pb >> 10) ? w2b : w1b;
    f32x4 v = *(const f32x4*)(src + (size_t)idx * 4);
    uint2 p;
    p.x = pack2(v.x, v.y);
    p.y = pack2(v.z, v.w);
    *(uint2*)(dst + (size_t)idx * 4) = p;
    return;
  }
  // ---- route branch
  __shared__ int s_lpos[NB];
  __shared__ int s_lbase[NB];
  __shared__ int s_b[256];
  const int base = bx * 256;
  const int token = base + tid;
  if (tid < NB) s_lpos[tid] = 0;
  __syncthreads();
  const int b = b_seq[token];
  s_b[tid] = b;
  int my = 0;
  if (b > 0) my = atomicAdd(&s_lpos[b - 1], 1);
  __syncthreads();
  if (tid < NB) s_lbase[tid] = atomicAdd(&counts[tid], s_lpos[tid]);
  __syncthreads();
  if (b > 0) lists[(b - 1) * TOK + s_lbase[b - 1] + my] = (ushort_t)token;
  // zero-fill rows with b==0, 16 B per store (64 u32x4 per row of 256 f32)
  const u32x4 z = (u32x4){0u, 0u, 0u, 0u};
  #pragma unroll 4
  for (int it = 0; it < 64; ++it) {
    int flat = it * 256 + tid;
    int tl = flat >> 6;          // wave-uniform row
    int j = flat & 63;
    if (s_b[tl] == 0) out16[(size_t)(base + tl) * 64 + j] = z;
  }
}

// ---------------- kernel 1: fused FFN + LN, single-barrier pipeline --------
// Round-4 lesson: keep waves UNIFORM (no role split; register asymmetry
// spilled -> +85 MB HBM traffic) and keep regs well under the cap.
// Round-3 lesson: LDS pipe ~78% busy is the limiter; barrier/drain overhead
// is per-iteration-constant.
// This version (block = 8 waves, M=64 tokens, 32 chunks of F=32):
//  * GEMM2 runs one chunk BEHIND GEMM1 (sH double-buffered) -> ONE
//    barrier+drain per iteration (33 total, was 64), one big sched region.
//  * GEMM2 re-tiled to wave=(dq 0..3, mh 0..1): 32 tok x 64 d with B-frag
//    reuse over mi2 -> W2 read 2x per block (was 4x). Block LDS reads/chunk:
//    112 b128 (was 136). yacc[2][4]=32 AGPR, xfrag[8]=32 VGPR (uniform).
//  * W1 DMA prefetched 1 chunk ahead; W2 DMA issued same-chunk (consumed
//    next iteration). Buffer parities verified disjoint.
__global__ __launch_bounds__(512, 4) void ffn_kernel(
    const float* __restrict__ x,
    const ushort_t* __restrict__ w1b_all, const float* __restrict__ b1,
    const ushort_t* __restrict__ w2b_all, const float* __restrict__ b2,
    const float* __restrict__ gamma, const float* __restrict__ beta,
    const int* __restrict__ counts, const ushort_t* __restrict__ lists,
    float* __restrict__ out)
{
  const int id = blockIdx.x;
  const int slot = id & 7;            // XCD affinity: branch n -> XCDs {2n,2n+1}
  const int n = slot >> 1;
  const int tile = ((id >> 3) << 1) + (slot & 1);
  const int cnt = counts[n];
  const int tile0 = tile * 64;
  if (tile0 >= cnt) return;           // block-uniform exit (before any barrier)
  const int mvalid = min(64, cnt - tile0);

  __shared__ __align__(16) ushort_t sW1[2][8192];   // 2 x 16KB (32f x 256k)
  __shared__ __align__(16) ushort_t sW2[2][8192];   // 2 x 16KB (256d x 32f)
  __shared__ __align__(16) ushort_t sH[2][64][40];  // H double-buffer
  __shared__ ushort_t sB1[DF];        // b1 as bf16 (exact for b1==0)
  __shared__ int s_idx[64];
  __shared__ float s_ps[4][64];
  __shared__ float s_pq[4][64];
  __shared__ float s_mu[64];
  __shared__ float s_rs[64];
  // total ~76.6 KB -> 2 blocks/CU

  ushort_t (*sX)[256] = (ushort_t (*)[256])&sW1[0][0];  // prologue alias 32KB

  const int tid  = threadIdx.x;
  const int wv   = tid >> 6;          // 0..7
  const int lane = tid & 63;
  const int q    = lane >> 4;
  const int lc   = lane & 15;
  const int fi   = wv & 1;            // GEMM1: f-sub (16 of the 32-chunk)
  const int mq   = wv >> 1;           // GEMM1: token quarter (16 rows)
  const int dq   = wv & 3;            // GEMM2: d-quarter (64 cols)
  const int mh   = wv >> 2;           // GEMM2: token half (32 rows)

  const ushort_t* w1b = w1b_all + (size_t)n * DF * DM;
  const ushort_t* w2b = w2b_all + (size_t)n * DM * DF;

  if (tid < 64) {
    int i = tile0 + tid;
    s_idx[tid] = (int)lists[n * TOK + (i < cnt ? i : tile0)];
  }
  // stage b1 slice as bf16 (1024 vals): 256 threads x 4
  if (tid < 256) {
    f32x4 v = *(const f32x4*)(b1 + n * DF + tid * 4);
    uint2 p;
    p.x = pack2(v.x, v.y);
    p.y = pack2(v.z, v.w);
    *(uint2*)(sB1 + tid * 4) = p;
  }
  __syncthreads();                    // B0: s_idx ready

  // ---- stage X tile 64x256 fp32 -> bf16 into sX, 16B-granule XOR swizzle
  #pragma unroll
  for (int it = 0; it < 4; ++it) {
    int flat = it * 512 + tid;
    int r = flat >> 5;                 // 0..63
    int c8 = flat & 31;                // 16B granule (8 bf16)
    const float* xp = x + (size_t)s_idx[r] * DM + c8 * 8;
    f32x4 a = *(const f32x4*)xp;
    f32x4 c = *(const f32x4*)(xp + 4);
    u32x4 p;
    p.x = pack2(a.x, a.y); p.y = pack2(a.z, a.w);
    p.z = pack2(c.x, c.y); p.w = pack2(c.z, c.w);
    *(u32x4*)(&sX[r][(c8 ^ (r & 31)) * 8]) = p;
  }
  __syncthreads();                    // B1: sX ready

  // ---- X A-frags to regs: this wave's 16 tokens x K=256 (32 VGPR)
  bf16x8 xfrag[8];
  #pragma unroll
  for (int ks = 0; ks < 8; ++ks) {
    int row = mq * 16 + lc;
    int g = (ks * 4 + q) ^ (row & 31);
    xfrag[ks] = *(const bf16x8*)(&sX[row][g * 8]);
  }
  __syncthreads();                    // B2: sX dead, W1 bufs free

  // W1 chunk fc -> sW1[fc&1]: 16 x 1KB segs over 8 waves (2/wave).
  // LDS[r][c] = G[r][c ^ r] (src-side swizzle; matches GEMM1 read).
  auto issue_w1 = [&](int fc) {
    ushort_t* dst = sW1[fc & 1];
    const ushort_t* g1 = w1b + (size_t)(fc * 32) * DM;
    #pragma unroll
    for (int j = 0; j < 2; ++j) {
      int i = wv * 2 + j;              // 0..15
      int s = i * 64 + lane;
      int r1 = s >> 5, cp1 = s & 31;
      dma16(g1 + (size_t)r1 * DM + (size_t)(cp1 ^ r1) * 8, dst + i * 512);
    }
  };
  // W2 chunk fc -> sW2[fc&1]: LDS[d][c] = G[d][c ^ (d&3) ^ ((d>>2)&3)].
  auto issue_w2 = [&](int fc) {
    ushort_t* dst = sW2[fc & 1];
    const ushort_t* g2 = w2b + fc * 32;
    #pragma unroll
    for (int j = 0; j < 2; ++j) {
      int i = wv * 2 + j;              // 0..15
      int s = i * 64 + lane;
      int d2 = s >> 2, cp2 = s & 3;
      int cps = cp2 ^ (d2 & 3) ^ ((d2 >> 2) & 3);
      dma16(g2 + (size_t)d2 * DF + (size_t)cps * 8, dst + i * 512);
    }
  };

  issue_w1(0);

  f32x4 yacc[2][4];       // [mi2][di]: 32 tok x 64 d (32 AGPR)
  #pragma unroll
  for (int mi2 = 0; mi2 < 2; ++mi2)
    #pragma unroll
    for (int di = 0; di < 4; ++di)
      yacc[mi2][di] = (f32x4){0.f, 0.f, 0.f, 0.f};

  const int r1row = fi * 16 + lc;     // GEMM1 W1 local row (0..31)
  const int cpw = (q ^ (lc & 3) ^ ((lc >> 2) & 3)) * 8;  // GEMM2 read swizzle

  // Pipeline: iter i runs GEMM1(i) [i<32] and GEMM2(i-1) [i>=1].
  // Entry barrier drains vmcnt(0)+lgkmcnt(0): W1(i) (issued i-1), W2(i-1)
  // (issued i-1), and all sH[i-1] ds_writes are then visible.
  #pragma unroll 1
  for (int i = 0; i <= 32; ++i) {
    __builtin_amdgcn_sched_barrier(0);
    __builtin_amdgcn_s_waitcnt(0x0070);     // vmcnt(0) lgkmcnt(0)
    __builtin_amdgcn_s_barrier();
    __builtin_amdgcn_sched_barrier(0);

    if (i < 31) issue_w1(i + 1);            // -> sW1[(i+1)&1]
    if (i < 32) issue_w2(i);                // -> sW2[i&1], read at iter i+1

    if (i < 32) {
      // ---- GEMM1(i): H[16 tok x 16 f] over K=256, two half-K chains
      const ushort_t* w1row = sW1[i & 1] + r1row * 256;
      const float b1v = bf2f(sB1[i * 32 + fi * 16 + lc]);
      f32x4 ha = (f32x4){0.f, 0.f, 0.f, 0.f};
      f32x4 hb = (f32x4){0.f, 0.f, 0.f, 0.f};
      __builtin_amdgcn_s_setprio(1);
      #pragma unroll
      for (int ks = 0; ks < 4; ++ks) {
        int cpa = ((2 * ks) * 4 + q) ^ r1row;
        int cpb = ((2 * ks + 1) * 4 + q) ^ r1row;
        bf16x8 bfa = *(const bf16x8*)(w1row + cpa * 8);
        bf16x8 bfb = *(const bf16x8*)(w1row + cpb * 8);
        ha = __builtin_amdgcn_mfma_f32_16x16x32_bf16(xfrag[2 * ks],     bfa, ha, 0, 0, 0);
        hb = __builtin_amdgcn_mfma_f32_16x16x32_bf16(xfrag[2 * ks + 1], bfb, hb, 0, 0, 0);
      }
      __builtin_amdgcn_s_setprio(0);
      #pragma unroll
      for (int r4 = 0; r4 < 4; ++r4) {
        float v = ha[r4] + hb[r4] + b1v;
        v = (v > 0.f) ? v : (__expf(v) - 1.f);
        sH[i & 1][mq * 16 + q * 4 + r4][fi * 16 + lc] = f2bf(v);
      }
    }

    if (i >= 1) {
      // ---- GEMM2(i-1): Y[32 tok x 64 d] += H[32 x 32] @ W2^T
      const int rb = (i - 1) & 1;
      bf16x8 af[2];
      #pragma unroll
      for (int mi2 = 0; mi2 < 2; ++mi2)
        af[mi2] = *(const bf16x8*)(&sH[rb][mh * 32 + mi2 * 16 + lc][q * 8]);
      const ushort_t* w2base = &sW2[rb][0] + (size_t)(dq * 64 + lc) * 32 + cpw;
      __builtin_amdgcn_s_setprio(1);
      #pragma unroll
      for (int di = 0; di < 4; ++di) {
        bf16x8 bf = *(const bf16x8*)(w2base + di * 512);
        yacc[0][di] = __builtin_amdgcn_mfma_f32_16x16x32_bf16(af[0], bf, yacc[0][di], 0, 0, 0);
        yacc[1][di] = __builtin_amdgcn_mfma_f32_16x16x32_bf16(af[1], bf, yacc[1][di], 0, 0, 0);
      }
      __builtin_amdgcn_s_setprio(0);
    }
  }

  // ================= epilogue: +b2, LN stats, gamma/beta, store =============
  __syncthreads();
  float b2v[4], gv[4], bv[4];
  #pragma unroll
  for (int di = 0; di < 4; ++di) {
    int dcol = n * DM + dq * 64 + di * 16 + lc;
    b2v[di] = b2[dcol];
    gv[di]  = gamma[dcol];
    bv[di]  = beta[dcol];
  }
  #pragma unroll
  for (int mi2 = 0; mi2 < 2; ++mi2)
    #pragma unroll
    for (int di = 0; di < 4; ++di)
      #pragma unroll
      for (int r4 = 0; r4 < 4; ++r4)
        yacc[mi2][di][r4] += b2v[di];

  #pragma unroll
  for (int mi2 = 0; mi2 < 2; ++mi2) {
    #pragma unroll
    for (int r4 = 0; r4 < 4; ++r4) {
      float s = 0.f, sq = 0.f;
      #pragma unroll
      for (int di = 0; di < 4; ++di) {
        float v = yacc[mi2][di][r4];
        s += v; sq += v * v;
      }
      #pragma unroll
      for (int off = 1; off < 16; off <<= 1) {
        s  += __shfl_xor(s, off, 64);
        sq += __shfl_xor(sq, off, 64);
      }
      if (lc == 0) {
        int tok = mh * 32 + mi2 * 16 + q * 4 + r4;
        s_ps[dq][tok] = s;
        s_pq[dq][tok] = sq;
      }
    }
  }
  __syncthreads();
  if (tid < 64) {
    float s  = s_ps[0][tid] + s_ps[1][tid] + s_ps[2][tid] + s_ps[3][tid];
    float sq = s_pq[0][tid] + s_pq[1][tid] + s_pq[2][tid] + s_pq[3][tid];
    float mu = s * (1.f / 256.f);
    float var = fmaxf(sq * (1.f / 256.f) - mu * mu, 0.f);
    s_mu[tid] = mu;
    s_rs[tid] = rsqrtf(var + 1e-12f);
  }
  __syncthreads();

  #pragma unroll
  for (int mi2 = 0; mi2 < 2; ++mi2) {
    #pragma unroll
    for (int r4 = 0; r4 < 4; ++r4) {
      int tok = mh * 32 + mi2 * 16 + q * 4 + r4;
      if (tok < mvalid) {
        float mu = s_mu[tok], rs = s_rs[tok];
        size_t rowbase = (size_t)s_idx[tok] * DM + dq * 64;
        #pragma unroll
        for (int di = 0; di < 4; ++di) {
          float v = (yacc[mi2][di][r4] - mu) * rs * gv[di] + bv[di];
          out[rowbase + di * 16 + lc] = v;
        }
      }
    }
  }
}

extern "C" void kernel_launch(void* const* d_in, const int* in_sizes, int n_in,
                              void* d_out, int out_size, void* d_ws, size_t ws_size,
                              hipStream_t stream) {
  const float* x     = (const float*)d_in[0];
  const int*   b_seq = (const int*)d_in[1];
  const float* w1    = (const float*)d_in[2];
  const float* b1    = (const float*)d_in[3];
  const float* w2    = (const float*)d_in[4];
  const float* b2    = (const float*)d_in[5];
  const float* gamma = (const float*)d_in[6];
  const float* beta  = (const float*)d_in[7];
  float* out = (float*)d_out;

  int* counts = (int*)d_ws;
  ushort_t* lists = (ushort_t*)((char*)d_ws + 256);                 // 512 KB
  ushort_t* w1b = (ushort_t*)((char*)d_ws + 256 + 512 * 1024);      // 2 MB
  ushort_t* w2b = w1b + (size_t)NB * DF * DM;                       // 2 MB

  hipMemsetAsync(counts, 0, 256, stream);
  // blocks [0,256): route; [256,2304): weight conversion
  hipLaunchKernelGGL(prep_route_kernel, dim3(2304), dim3(256), 0, stream,
                     w1, w2, w1b, w2b, b_seq, counts, lists, (u32x4*)d_out);
  // 1024 tiles/branch capacity: covers any branch imbalance up to 65536
  hipLaunchKernelGGL(ffn_kernel, dim3(4096), dim3(512), 0, stream,
                     x, w1b, b1, w2b, b2, gamma, beta, counts, lists, out);
}